// Round 1
// baseline (318.874 us; speedup 1.0000x reference)
//
#include <hip/hip_runtime.h>
#include <hip/hip_bf16.h>

typedef unsigned short ushort_t;
typedef unsigned int uint_t;

typedef __attribute__((ext_vector_type(8))) short bf16x8;
typedef __attribute__((ext_vector_type(4))) float f32x4;
typedef __attribute__((ext_vector_type(8))) unsigned short u16x8;

constexpr int Mdim = 4096;  // tokens
constexpr int Ndim = 4096;  // out features
constexpr int Kdim = 4096;  // in features

__device__ __forceinline__ ushort_t f2bf(float f) {
  uint_t u = __float_as_uint(f);
  u += 0x7fffu + ((u >> 16) & 1u);   // round-to-nearest-even
  return (ushort_t)(u >> 16);
}

// ---------------- pre-pass 1: x f32 -> bf16 ----------------
__global__ void __launch_bounds__(256) cvt_x_kernel(const float* __restrict__ x,
                                                    ushort_t* __restrict__ xb) {
  const size_t t = (size_t)blockIdx.x * 256 + threadIdx.x;
  const float4* p = reinterpret_cast<const float4*>(x) + t * 2;
  float4 a = p[0], b = p[1];
  u16x8 o;
  o[0] = f2bf(a.x); o[1] = f2bf(a.y); o[2] = f2bf(a.z); o[3] = f2bf(a.w);
  o[4] = f2bf(b.x); o[5] = f2bf(b.y); o[6] = f2bf(b.z); o[7] = f2bf(b.w);
  *reinterpret_cast<u16x8*>(xb + t * 8) = o;
}

// ---------------- pre-pass 2: bitmasks -> bf16 W [N][K] ----------------
__global__ void __launch_bounds__(256) unpack_w_kernel(const int* __restrict__ pos,
                                                       const int* __restrict__ neg,
                                                       ushort_t* __restrict__ wb) {
  const size_t t = (size_t)blockIdx.x * 256 + threadIdx.x;
  const int4 p = reinterpret_cast<const int4*>(pos)[t];
  const int4 q = reinterpret_cast<const int4*>(neg)[t];
  const int pv[4] = {p.x, p.y, p.z, p.w};
  const int nv[4] = {q.x, q.y, q.z, q.w};
  ushort_t* dst = wb + t * 32;
#pragma unroll
  for (int e = 0; e < 4; ++e) {
    u16x8 v;
#pragma unroll
    for (int j = 0; j < 8; ++j) {
      const int pb = (pv[e] >> (7 - j)) & 1;
      const int nb = (nv[e] >> (7 - j)) & 1;
      const int d = pb - nb;                     // {-1,0,+1}
      v[j] = (d == 1) ? (ushort_t)0x3F80 : ((d == -1) ? (ushort_t)0xBF80 : (ushort_t)0);
    }
    *reinterpret_cast<u16x8*>(dst + e * 8) = v;
  }
}

// ---------------- GEMM: C[M][N] = scale * A[M][K] x B[N][K]^T + bias ----------------
#define GLD16(gp, lp)                                                     \
  __builtin_amdgcn_global_load_lds(                                       \
      (const __attribute__((address_space(1))) void*)(gp),                \
      (__attribute__((address_space(3))) void*)(lp), 16, 0, 0)

__global__ void __launch_bounds__(256) gemm_kernel(const ushort_t* __restrict__ A,
                                                   const ushort_t* __restrict__ B,
                                                   float* __restrict__ C,
                                                   const float* __restrict__ scale_p,
                                                   const float* __restrict__ bias) {
  constexpr int BM = 128, BN = 128, BK = 32;
  __shared__ ushort_t As[BM * BK];
  __shared__ ushort_t Bs[BN * BK];

  const int m0 = blockIdx.y * BM;
  const int n0 = blockIdx.x * BN;
  const int tid = threadIdx.x;
  const int wid = tid >> 6;
  const int lane = tid & 63;
  const int wr = wid >> 1, wc = wid & 1;       // 2x2 waves, each owns 64x64
  const int lrow = lane & 15;
  const int lk = (lane >> 4) * 8;              // k-offset of this lane's fragment

  // staging geometry: tile is BM x BK bf16 = 8192 B = 512 segments of 16 B
  // segment s -> row s>>2, byte-col (s&3)*16
  const int segA0 = tid, segA1 = tid + 256;
  const int rA0 = segA0 >> 2, cA0 = (segA0 & 3) * 16;
  const int rA1 = segA1 >> 2, cA1 = (segA1 & 3) * 16;

  const char* gA0 = (const char*)A + ((size_t)(m0 + rA0) * Kdim) * 2 + cA0;
  const char* gA1 = (const char*)A + ((size_t)(m0 + rA1) * Kdim) * 2 + cA1;
  const char* gB0 = (const char*)B + ((size_t)(n0 + rA0) * Kdim) * 2 + cA0;
  const char* gB1 = (const char*)B + ((size_t)(n0 + rA1) * Kdim) * 2 + cA1;

  // wave-uniform LDS bases: each global_load_lds writes 64 lanes x 16 B = 1024 B
  char* lA0 = (char*)As + (size_t)wid * 1024;
  char* lA1 = (char*)As + 4096 + (size_t)wid * 1024;
  char* lB0 = (char*)Bs + (size_t)wid * 1024;
  char* lB1 = (char*)Bs + 4096 + (size_t)wid * 1024;

  f32x4 acc[4][4] = {};

  for (int kt = 0; kt < Kdim / BK; ++kt) {
    const size_t koff = (size_t)kt * (BK * 2);  // 64 bytes per k-step
    GLD16(gA0 + koff, lA0);
    GLD16(gA1 + koff, lA1);
    GLD16(gB0 + koff, lB0);
    GLD16(gB1 + koff, lB1);
    __syncthreads();  // drains vmcnt(0) before barrier -> LDS tiles ready

    bf16x8 af[4], bg[4];
#pragma unroll
    for (int am = 0; am < 4; ++am)
      af[am] = *reinterpret_cast<const bf16x8*>(&As[(wr * 64 + am * 16 + lrow) * BK + lk]);
#pragma unroll
    for (int bn = 0; bn < 4; ++bn)
      bg[bn] = *reinterpret_cast<const bf16x8*>(&Bs[(wc * 64 + bn * 16 + lrow) * BK + lk]);

#pragma unroll
    for (int am = 0; am < 4; ++am)
#pragma unroll
      for (int bn = 0; bn < 4; ++bn)
        acc[am][bn] = __builtin_amdgcn_mfma_f32_16x16x32_bf16(af[am], bg[bn], acc[am][bn], 0, 0, 0);

    __syncthreads();  // all reads done before next stage overwrites
  }

  // epilogue: C/D layout col = lane&15, row = (lane>>4)*4 + reg
  const float s = *scale_p;
  const int rbase = m0 + wr * 64 + (lane >> 4) * 4;
  const int cbase = n0 + wc * 64 + lrow;
#pragma unroll
  for (int bn = 0; bn < 4; ++bn) {
    const int col = cbase + bn * 16;
    const float bv = bias[col];
#pragma unroll
    for (int am = 0; am < 4; ++am) {
      const int row0 = rbase + am * 16;
#pragma unroll
      for (int r = 0; r < 4; ++r) {
        C[(size_t)(row0 + r) * Ndim + col] = s * acc[am][bn][r] + bv;
      }
    }
  }
}

extern "C" void kernel_launch(void* const* d_in, const int* in_sizes, int n_in,
                              void* d_out, int out_size, void* d_ws, size_t ws_size,
                              hipStream_t stream) {
  const float* x = (const float*)d_in[0];
  const int* pos = (const int*)d_in[1];
  const int* neg = (const int*)d_in[2];
  const float* scale = (const float*)d_in[3];
  const float* bias = (const float*)d_in[4];
  float* out = (float*)d_out;

  ushort_t* xb = (ushort_t*)d_ws;                        // 32 MB: x as bf16 [M][K]
  ushort_t* wb = xb + (size_t)Mdim * Kdim;               // 32 MB: W as bf16 [N][K]

  // x: 16,777,216 elems, 8 per thread -> 8192 blocks
  cvt_x_kernel<<<(Mdim * Kdim) / (256 * 8), 256, 0, stream>>>(x, xb);
  // masks: 2,097,152 int32 entries, 4 per thread -> 2048 blocks
  unpack_w_kernel<<<(Ndim * (Kdim / 8)) / (256 * 4), 256, 0, stream>>>(pos, neg, wb);
  // GEMM: 32 x 32 blocks of 128x128
  gemm_kernel<<<dim3(Ndim / 128, Mdim / 128), 256, 0, stream>>>(xb, wb, out, scale, bias);
}

// Round 2
// 242.450 us; speedup vs baseline: 1.3152x; 1.3152x over previous
//
#include <hip/hip_runtime.h>
#include <hip/hip_bf16.h>

typedef unsigned short ushort_t;
typedef unsigned int uint_t;

typedef __attribute__((ext_vector_type(8))) short bf16x8;
typedef __attribute__((ext_vector_type(4))) float f32x4;
typedef __attribute__((ext_vector_type(8))) unsigned short u16x8;

constexpr int Mdim = 4096;  // tokens
constexpr int Ndim = 4096;  // out features
constexpr int Kdim = 4096;  // in features
constexpr int K2 = Kdim * 2;          // global row stride in bytes
constexpr int NIT = Kdim / 128;       // 32 iterations, 2 K-tiles (BK=64) each

__device__ __forceinline__ ushort_t f2bf(float f) {
  uint_t u = __float_as_uint(f);
  u += 0x7fffu + ((u >> 16) & 1u);   // round-to-nearest-even
  return (ushort_t)(u >> 16);
}

// ---------------- pre-pass 1: x f32 -> bf16 ----------------
__global__ void __launch_bounds__(256) cvt_x_kernel(const float* __restrict__ x,
                                                    ushort_t* __restrict__ xb) {
  const size_t t = (size_t)blockIdx.x * 256 + threadIdx.x;
  const float4* p = reinterpret_cast<const float4*>(x) + t * 2;
  float4 a = p[0], b = p[1];
  u16x8 o;
  o[0] = f2bf(a.x); o[1] = f2bf(a.y); o[2] = f2bf(a.z); o[3] = f2bf(a.w);
  o[4] = f2bf(b.x); o[5] = f2bf(b.y); o[6] = f2bf(b.z); o[7] = f2bf(b.w);
  *reinterpret_cast<u16x8*>(xb + t * 8) = o;
}

// ---------------- pre-pass 2: bitmasks -> bf16 W [N][K] ----------------
__global__ void __launch_bounds__(256) unpack_w_kernel(const int* __restrict__ pos,
                                                       const int* __restrict__ neg,
                                                       ushort_t* __restrict__ wb) {
  const size_t t = (size_t)blockIdx.x * 256 + threadIdx.x;
  const int4 p = reinterpret_cast<const int4*>(pos)[t];
  const int4 q = reinterpret_cast<const int4*>(neg)[t];
  const int pv[4] = {p.x, p.y, p.z, p.w};
  const int nv[4] = {q.x, q.y, q.z, q.w};
  ushort_t* dst = wb + t * 32;
#pragma unroll
  for (int e = 0; e < 4; ++e) {
    u16x8 v;
#pragma unroll
    for (int j = 0; j < 8; ++j) {
      const int pb = (pv[e] >> (7 - j)) & 1;
      const int nb = (nv[e] >> (7 - j)) & 1;
      const int d = pb - nb;                     // {-1,0,+1}
      v[j] = (d == 1) ? (ushort_t)0x3F80 : ((d == -1) ? (ushort_t)0xBF80 : (ushort_t)0);
    }
    *reinterpret_cast<u16x8*>(dst + e * 8) = v;
  }
}

// ---------------- 256x256 8-phase GEMM: C = scale * A[M][K] x B[N][K]^T + bias ----------------
#define GLD16(gp, lp)                                                     \
  __builtin_amdgcn_global_load_lds(                                       \
      (const __attribute__((address_space(1))) void*)(gp),                \
      (__attribute__((address_space(3))) void*)(lp), 16, 0, 0)

#define VMCNT(N) asm volatile("s_waitcnt vmcnt(" #N ")" ::: "memory")

#define BARRIER() do {                          \
  __builtin_amdgcn_sched_barrier(0);            \
  __builtin_amdgcn_s_barrier();                 \
  __builtin_amdgcn_sched_barrier(0);            \
} while (0)

// LDS map (131072 B total):
//   A: buf*32768 + half*16384 + row*128 + swizzled_col   (bufs at 0, 32768)
//   B: 65536 + buf*32768 + half*16384 + row*128 + swizzled_col
// Swizzle (T2, G4-style, involution): phys_col = logical_col ^ ((row&7)<<4)

#define STAGE_A(BUF, HALF, KT) do {                                                    \
  const char* g_ = Ab + gAoff + (size_t)(HALF) * (128 * (size_t)K2) + (size_t)(KT) * 128; \
  char* l_ = ldsw + (BUF) * 32768 + (HALF) * 16384;                                    \
  GLD16(g_, l_);                                                                       \
  GLD16(g_ + (size_t)64 * K2, l_ + 8192);                                              \
} while (0)

#define STAGE_B(BUF, HALF, KT) do {                                                    \
  const char* g_ = Bb + gBoff + (size_t)(HALF) * (128 * (size_t)K2) + (size_t)(KT) * 128; \
  char* l_ = ldsw + 65536 + (BUF) * 32768 + (HALF) * 16384;                            \
  GLD16(g_, l_);                                                                       \
  GLD16(g_ + (size_t)64 * K2, l_ + 8192);                                              \
} while (0)

#define LDA(BUF, M, KK) (*(const bf16x8*)(lds + (BUF) * 32768 + aRowBase + (M) * 2048 + acol[KK]))
#define LDB(BUF, N, KK) (*(const bf16x8*)(lds + 65536 + (BUF) * 32768 + bRowBase + (N) * 2048 + acol[KK]))

// One phase: {ds-read A-quadrant (+ all B frags if Q==0); issue stage; barrier;
//             MFMA cluster (setprio-wrapped); [vmcnt]; barrier}
#define PHASE(BUF, Q, PREBAR2, ...) do {                                               \
  bf16x8 a0k0 = LDA(BUF, 2*(Q),   0), a0k1 = LDA(BUF, 2*(Q),   1);                     \
  bf16x8 a1k0 = LDA(BUF, 2*(Q)+1, 0), a1k1 = LDA(BUF, 2*(Q)+1, 1);                     \
  if ((Q) == 0) {                                                                      \
    _Pragma("unroll")                                                                  \
    for (int n_ = 0; n_ < 4; ++n_) { vb[n_][0] = LDB(BUF, n_, 0); vb[n_][1] = LDB(BUF, n_, 1); } \
  }                                                                                    \
  __VA_ARGS__;                                                                         \
  BARRIER();                                                                           \
  __builtin_amdgcn_s_setprio(1);                                                       \
  _Pragma("unroll")                                                                    \
  for (int n_ = 0; n_ < 4; ++n_) {                                                     \
    acc[2*(Q)][n_]   = __builtin_amdgcn_mfma_f32_16x16x32_bf16(a0k0, vb[n_][0], acc[2*(Q)][n_],   0, 0, 0); \
    acc[2*(Q)+1][n_] = __builtin_amdgcn_mfma_f32_16x16x32_bf16(a1k0, vb[n_][0], acc[2*(Q)+1][n_], 0, 0, 0); \
  }                                                                                    \
  _Pragma("unroll")                                                                    \
  for (int n_ = 0; n_ < 4; ++n_) {                                                     \
    acc[2*(Q)][n_]   = __builtin_amdgcn_mfma_f32_16x16x32_bf16(a0k1, vb[n_][1], acc[2*(Q)][n_],   0, 0, 0); \
    acc[2*(Q)+1][n_] = __builtin_amdgcn_mfma_f32_16x16x32_bf16(a1k1, vb[n_][1], acc[2*(Q)+1][n_], 0, 0, 0); \
  }                                                                                    \
  __builtin_amdgcn_s_setprio(0);                                                       \
  PREBAR2;                                                                             \
  BARRIER();                                                                           \
} while (0)

__global__ void __launch_bounds__(512, 2) gemm_kernel(const ushort_t* __restrict__ A,
                                                      const ushort_t* __restrict__ B,
                                                      float* __restrict__ C,
                                                      const float* __restrict__ scale_p,
                                                      const float* __restrict__ bias) {
  __shared__ char lds[131072];

  // T1: XCD-aware block swizzle (256 wgs, 8 XCDs, bijective)
  const int bid = blockIdx.x;
  const int swz = (bid & 7) * 32 + (bid >> 3);
  const int m0 = (swz >> 4) * 256;
  const int n0 = (swz & 15) * 256;

  const int tid = threadIdx.x;
  const int wid = tid >> 6;
  const int lane = tid & 63;
  const int wr = wid >> 2;   // 0..1 -> M half
  const int wc = wid & 3;    // 0..3 -> N quarter

  // Pin scale/bias loads before the counted-vmcnt region
  float sv = *scale_p;
  float bv[4];
#pragma unroll
  for (int n = 0; n < 4; ++n) bv[n] = bias[n0 + wc * 64 + n * 16 + (lane & 15)];
  asm volatile("" : "+v"(sv), "+v"(bv[0]), "+v"(bv[1]), "+v"(bv[2]), "+v"(bv[3]));

  // Staging addressing: thread covers segment s = j*512 + tid (j=0,1) of each 16KB half-tile.
  // LDS dest linear; global source col pre-swizzled so that swizzled ds_read sees logical data.
  const int srow = tid >> 3;                                  // 0..63
  const int scol = 16 * ((tid & 7) ^ (srow & 7));             // pre-swizzled source col-byte
  const char* Ab = (const char*)A;
  const char* Bb = (const char*)B;
  const size_t gAoff = (size_t)(m0 + srow) * K2 + scol;
  const size_t gBoff = (size_t)(n0 + srow) * K2 + scol;
  char* ldsw = lds + wid * 1024;   // wave-uniform LDS base component

  // Fragment read addressing (swizzled col)
  const int acol[2] = { (0  + ((lane >> 4) << 4)) ^ ((lane & 7) << 4),
                        (64 + ((lane >> 4) << 4)) ^ ((lane & 7) << 4) };
  const int aRowBase = wr * 16384 + (lane & 15) * 128;
  const int bRowBase = (wc >> 1) * 16384 + ((wc & 1) * 64 + (lane & 15)) * 128;

  f32x4 acc[8][4] = {};
  bf16x8 vb[4][2];

  // Prologue: tile0 fully (buf0) + tile1's B (buf1); wait tile0, leave tile1.B in flight.
  STAGE_B(0, 0, 0); STAGE_B(0, 1, 0);
  STAGE_A(0, 0, 0); STAGE_A(0, 1, 0);
  STAGE_B(1, 0, 1); STAGE_B(1, 1, 1);
  VMCNT(4);
  BARRIER();

#pragma unroll 1
  for (int i = 0; i < NIT - 1; ++i) {
    const int t0 = 2 * i, t1 = 2 * i + 1;
    // tile t0 in buf0
    PHASE(0, 0, ,      STAGE_A(1, 0, t1); STAGE_A(1, 1, t1));   // buf1.A free since prev ph7
    PHASE(0, 1, ,      STAGE_B(0, 0, t0 + 2));                  // buf0.B free after ph0
    PHASE(0, 2, ,      STAGE_B(0, 1, t0 + 2));
    PHASE(0, 3, VMCNT(4), );                                    // guard tile t1 (A@ph0, B@prev ph6/7)
    // tile t1 in buf1
    PHASE(1, 0, ,      STAGE_A(0, 0, t0 + 2));                  // buf0.A free after ph3
    PHASE(1, 1, ,      STAGE_A(0, 1, t0 + 2));
    PHASE(1, 2, ,      STAGE_B(1, 0, t1 + 2));                  // buf1.B free after ph4
    PHASE(1, 3, VMCNT(4), STAGE_B(1, 1, t1 + 2));               // guard tile t0+2
  }
  {
    // Final iteration: tiles 62 (buf0), 63 (buf1); only A(63) still to stage.
    PHASE(0, 0, ,      STAGE_A(1, 0, 2 * NIT - 1); STAGE_A(1, 1, 2 * NIT - 1));
    PHASE(0, 1, , );
    PHASE(0, 2, , );
    PHASE(0, 3, VMCNT(0), );
    PHASE(1, 0, , );
    PHASE(1, 1, , );
    PHASE(1, 2, , );
    PHASE(1, 3, , );
  }

  // Epilogue: C/D layout col = lane&15, row = (lane>>4)*4 + reg
  const int row0 = m0 + wr * 128 + ((lane >> 4) << 2);
  const int col0 = n0 + wc * 64 + (lane & 15);
#pragma unroll
  for (int m = 0; m < 8; ++m)
#pragma unroll
    for (int n = 0; n < 4; ++n) {
      const int c = col0 + n * 16;
#pragma unroll
      for (int k = 0; k < 4; ++k)
        C[(size_t)(row0 + m * 16 + k) * Ndim + c] = sv * acc[m][n][k] + bv[n];
    }
}

extern "C" void kernel_launch(void* const* d_in, const int* in_sizes, int n_in,
                              void* d_out, int out_size, void* d_ws, size_t ws_size,
                              hipStream_t stream) {
  const float* x = (const float*)d_in[0];
  const int* pos = (const int*)d_in[1];
  const int* neg = (const int*)d_in[2];
  const float* scale = (const float*)d_in[3];
  const float* bias = (const float*)d_in[4];
  float* out = (float*)d_out;

  ushort_t* xb = (ushort_t*)d_ws;                        // 32 MB: x as bf16 [M][K]
  ushort_t* wb = xb + (size_t)Mdim * Kdim;               // 32 MB: W as bf16 [N][K]

  cvt_x_kernel<<<(Mdim * Kdim) / (256 * 8), 256, 0, stream>>>(x, xb);
  unpack_w_kernel<<<(Ndim * (Kdim / 8)) / (256 * 4), 256, 0, stream>>>(pos, neg, wb);
  gemm_kernel<<<dim3((Mdim / 256) * (Ndim / 256)), 512, 0, stream>>>(xb, wb, out, scale, bias);
}

// Round 3
// 239.928 us; speedup vs baseline: 1.3290x; 1.0105x over previous
//
#include <hip/hip_runtime.h>
#include <hip/hip_bf16.h>

typedef unsigned short ushort_t;
typedef unsigned int uint_t;

typedef __attribute__((ext_vector_type(8))) short bf16x8;
typedef __attribute__((ext_vector_type(4))) float f32x4;
typedef __attribute__((ext_vector_type(8))) unsigned short u16x8;

constexpr int Mdim = 4096;  // tokens
constexpr int Ndim = 4096;  // out features
constexpr int Kdim = 4096;  // in features
constexpr int K2 = Kdim * 2;          // global row stride in bytes
constexpr int NIT = Kdim / 128;       // 32 iterations, 2 K-tiles (BK=64) each

__device__ __forceinline__ ushort_t f2bf(float f) {
  uint_t u = __float_as_uint(f);
  u += 0x7fffu + ((u >> 16) & 1u);   // round-to-nearest-even
  return (ushort_t)(u >> 16);
}

// ---------------- pre-pass 1: x f32 -> bf16 ----------------
__global__ void __launch_bounds__(256) cvt_x_kernel(const float* __restrict__ x,
                                                    ushort_t* __restrict__ xb) {
  const size_t t = (size_t)blockIdx.x * 256 + threadIdx.x;
  const float4* p = reinterpret_cast<const float4*>(x) + t * 2;
  float4 a = p[0], b = p[1];
  u16x8 o;
  o[0] = f2bf(a.x); o[1] = f2bf(a.y); o[2] = f2bf(a.z); o[3] = f2bf(a.w);
  o[4] = f2bf(b.x); o[5] = f2bf(b.y); o[6] = f2bf(b.z); o[7] = f2bf(b.w);
  *reinterpret_cast<u16x8*>(xb + t * 8) = o;
}

// ---------------- pre-pass 2: bitmasks -> bf16 W [N][K] ----------------
__global__ void __launch_bounds__(256) unpack_w_kernel(const int* __restrict__ pos,
                                                       const int* __restrict__ neg,
                                                       ushort_t* __restrict__ wb) {
  const size_t t = (size_t)blockIdx.x * 256 + threadIdx.x;
  const int4 p = reinterpret_cast<const int4*>(pos)[t];
  const int4 q = reinterpret_cast<const int4*>(neg)[t];
  const int pv[4] = {p.x, p.y, p.z, p.w};
  const int nv[4] = {q.x, q.y, q.z, q.w};
  ushort_t* dst = wb + t * 32;
#pragma unroll
  for (int e = 0; e < 4; ++e) {
    u16x8 v;
#pragma unroll
    for (int j = 0; j < 8; ++j) {
      const int pb = (pv[e] >> (7 - j)) & 1;
      const int nb = (nv[e] >> (7 - j)) & 1;
      const int d = pb - nb;                     // {-1,0,+1}
      v[j] = (d == 1) ? (ushort_t)0x3F80 : ((d == -1) ? (ushort_t)0xBF80 : (ushort_t)0);
    }
    *reinterpret_cast<u16x8*>(dst + e * 8) = v;
  }
}

// ---------------- 256x256 pipelined 8-window GEMM ----------------
#define GLD16(gp, lp)                                                     \
  __builtin_amdgcn_global_load_lds(                                       \
      (const __attribute__((address_space(1))) void*)(gp),                \
      (__attribute__((address_space(3))) void*)(lp), 16, 0, 0)

#define VMCNT(N) asm volatile("s_waitcnt vmcnt(" #N ")" ::: "memory")

#define BARRIER() do {                          \
  __builtin_amdgcn_sched_barrier(0);            \
  __builtin_amdgcn_s_barrier();                 \
  __builtin_amdgcn_sched_barrier(0);            \
} while (0)

// LDS map (131072 B total):
//   A: buf*32768 + half*16384 + row*128 + swizzled_col   (bufs at 0, 32768)
//   B: 65536 + buf*32768 + half*16384 + row*128 + swizzled_col
// Swizzle (T2, involution): phys_col = logical_col ^ ((row&7)<<4)

#define STAGE_A(BUF, HALF, KT) do {                                                    \
  const char* g_ = Ab + gAoff + (size_t)(HALF) * (128 * (size_t)K2) + (size_t)(KT) * 128; \
  char* l_ = ldsw + (BUF) * 32768 + (HALF) * 16384;                                    \
  GLD16(g_, l_);                                                                       \
  GLD16(g_ + (size_t)64 * K2, l_ + 8192);                                              \
} while (0)

#define STAGE_B(BUF, HALF, KT) do {                                                    \
  const char* g_ = Bb + gBoff + (size_t)(HALF) * (128 * (size_t)K2) + (size_t)(KT) * 128; \
  char* l_ = ldsw + 65536 + (BUF) * 32768 + (HALF) * 16384;                            \
  GLD16(g_, l_);                                                                       \
  GLD16(g_ + (size_t)64 * K2, l_ + 8192);                                              \
} while (0)

#define LDA(BUF, M, KK) (*(const bf16x8*)(lds + (BUF) * 32768 + aRowBase + (M) * 2048 + acol[KK]))
#define LDB(BUF, N, KK) (*(const bf16x8*)(lds + 65536 + (BUF) * 32768 + bRowBase + (N) * 2048 + acol[KK]))

// Prefetch A fragments for quadrant RQ of buffer RB into register bank BANK
#define READS_A(BANK, RB, RQ) do {                                                     \
  af##BANK[0] = LDA(RB, 2*(RQ),   0); af##BANK[1] = LDA(RB, 2*(RQ),   1);              \
  af##BANK[2] = LDA(RB, 2*(RQ)+1, 0); af##BANK[3] = LDA(RB, 2*(RQ)+1, 1);              \
} while (0)

// Load all B fragments of buffer CB (consumed by the following 4 windows)
#define READS_B(CB) do {                                                               \
  _Pragma("unroll")                                                                    \
  for (int n_ = 0; n_ < 4; ++n_) { vb[n_][0] = LDB(CB, n_, 0); vb[n_][1] = LDB(CB, n_, 1); } \
} while (0)

// 16 MFMAs on register bank BANK for output quadrant Q
#define MFMA16(BANK, Q) do {                                                           \
  __builtin_amdgcn_s_setprio(1);                                                       \
  _Pragma("unroll")                                                                    \
  for (int n_ = 0; n_ < 4; ++n_) {                                                     \
    acc[2*(Q)][n_]   = __builtin_amdgcn_mfma_f32_16x16x32_bf16(af##BANK[0], vb[n_][0], acc[2*(Q)][n_],   0, 0, 0); \
    acc[2*(Q)+1][n_] = __builtin_amdgcn_mfma_f32_16x16x32_bf16(af##BANK[2], vb[n_][0], acc[2*(Q)+1][n_], 0, 0, 0); \
  }                                                                                    \
  _Pragma("unroll")                                                                    \
  for (int n_ = 0; n_ < 4; ++n_) {                                                     \
    acc[2*(Q)][n_]   = __builtin_amdgcn_mfma_f32_16x16x32_bf16(af##BANK[1], vb[n_][1], acc[2*(Q)][n_],   0, 0, 0); \
    acc[2*(Q)+1][n_] = __builtin_amdgcn_mfma_f32_16x16x32_bf16(af##BANK[3], vb[n_][1], acc[2*(Q)+1][n_], 0, 0, 0); \
  }                                                                                    \
  __builtin_amdgcn_s_setprio(0);                                                       \
} while (0)

__global__ void __launch_bounds__(512, 2) gemm_kernel(const ushort_t* __restrict__ A,
                                                      const ushort_t* __restrict__ B,
                                                      float* __restrict__ C,
                                                      const float* __restrict__ scale_p,
                                                      const float* __restrict__ bias) {
  __shared__ char lds[131072];

  // T1: XCD-aware block swizzle (256 wgs, 8 XCDs, bijective)
  const int bid = blockIdx.x;
  const int swz = (bid & 7) * 32 + (bid >> 3);
  const int m0 = (swz >> 4) * 256;
  const int n0 = (swz & 15) * 256;

  const int tid = threadIdx.x;
  const int wid = tid >> 6;
  const int lane = tid & 63;
  const int wr = wid >> 2;   // 0..1 -> M half
  const int wc = wid & 3;    // 0..3 -> N quarter

  // Pin scale/bias loads before the counted-vmcnt region
  float sv = *scale_p;
  float bv[4];
#pragma unroll
  for (int n = 0; n < 4; ++n) bv[n] = bias[n0 + wc * 64 + n * 16 + (lane & 15)];
  asm volatile("" : "+v"(sv), "+v"(bv[0]), "+v"(bv[1]), "+v"(bv[2]), "+v"(bv[3]));

  // Staging addressing: thread covers segment s = tid of each 8KB region.
  // LDS dest linear; global source col pre-swizzled (involution) so swizzled ds_read sees logical data.
  const int srow = tid >> 3;                                  // 0..63
  const int scol = 16 * ((tid & 7) ^ (srow & 7));             // pre-swizzled source col-byte
  const char* Ab = (const char*)A;
  const char* Bb = (const char*)B;
  const size_t gAoff = (size_t)(m0 + srow) * K2 + scol;
  const size_t gBoff = (size_t)(n0 + srow) * K2 + scol;
  char* ldsw = lds + wid * 1024;   // wave-uniform LDS base component

  // Fragment read addressing (swizzled col)
  const int acol[2] = { (0  + ((lane >> 4) << 4)) ^ ((lane & 7) << 4),
                        (64 + ((lane >> 4) << 4)) ^ ((lane & 7) << 4) };
  const int aRowBase = wr * 16384 + (lane & 15) * 128;
  const int bRowBase = (wc >> 1) * 16384 + ((wc & 1) * 64 + (lane & 15)) * 128;

  f32x4 acc[8][4] = {};
  bf16x8 af0[4], af1[4];    // double-banked A fragments (pipelined one window ahead)
  bf16x8 vb[4][2];          // B fragments for the current tile (read in Q0 windows)

  // Prologue: stage tile0 (buf0: B then A) + tile1's B (buf1); drain tile0; prefetch W0's A frags.
  STAGE_B(0, 0, 0); STAGE_B(0, 1, 0);
  STAGE_A(0, 0, 0); STAGE_A(0, 1, 0);
  STAGE_B(1, 0, 1); STAGE_B(1, 1, 1);
  VMCNT(4);
  BARRIER();
  READS_A(0, 0, 0);

#pragma unroll 1
  for (int i = 0; i < NIT - 1; ++i) {
    const int t1 = 2 * i + 1, tn = 2 * i + 2;
    // ---- tile t0 (buf0) ----
    BARRIER(); STAGE_A(1, 0, t1); STAGE_A(1, 1, t1);
               READS_B(0); READS_A(1, 0, 1); MFMA16(0, 0);          // W0
    BARRIER(); STAGE_B(0, 0, tn);
               READS_A(0, 0, 2); MFMA16(1, 1);                      // W1
    BARRIER(); STAGE_B(0, 1, tn);
               READS_A(1, 0, 3); MFMA16(0, 2);                      // W2
    VMCNT(4);
    BARRIER(); READS_A(0, 1, 0); MFMA16(1, 3);                      // W3 (publishes buf1)
    // ---- tile t1 (buf1) ----
    BARRIER(); STAGE_A(0, 0, tn);
               READS_B(1); READS_A(1, 1, 1); MFMA16(0, 0);          // W4
    BARRIER(); STAGE_A(0, 1, tn);
               READS_A(0, 1, 2); MFMA16(1, 1);                      // W5
    BARRIER(); STAGE_B(1, 0, t1 + 2);
               READS_A(1, 1, 3); MFMA16(0, 2);                      // W6
    VMCNT(2);
    BARRIER(); STAGE_B(1, 1, t1 + 2);
               READS_A(0, 0, 0); MFMA16(1, 3);                      // W7 (publishes buf0 A)
  }
  {
    // Final iteration: tiles 2*NIT-2 (buf0), 2*NIT-1 (buf1); only A(last) still to stage.
    BARRIER(); STAGE_A(1, 0, 2 * NIT - 1); STAGE_A(1, 1, 2 * NIT - 1);
               READS_B(0); READS_A(1, 0, 1); MFMA16(0, 0);          // W0
    BARRIER(); READS_A(0, 0, 2); MFMA16(1, 1);                      // W1
    BARRIER(); READS_A(1, 0, 3); MFMA16(0, 2);                      // W2
    VMCNT(0);
    BARRIER(); READS_A(0, 1, 0); MFMA16(1, 3);                      // W3
    BARRIER(); READS_B(1); READS_A(1, 1, 1); MFMA16(0, 0);          // W4
    BARRIER(); READS_A(0, 1, 2); MFMA16(1, 1);                      // W5
    BARRIER(); READS_A(1, 1, 3); MFMA16(0, 2);                      // W6
    BARRIER(); MFMA16(1, 3);                                        // W7
  }

  // Epilogue: C/D layout col = lane&15, row = (lane>>4)*4 + reg
  const int row0 = m0 + wr * 128 + ((lane >> 4) << 2);
  const int col0 = n0 + wc * 64 + (lane & 15);
#pragma unroll
  for (int m = 0; m < 8; ++m)
#pragma unroll
    for (int n = 0; n < 4; ++n) {
      const int c = col0 + n * 16;
#pragma unroll
      for (int k = 0; k < 4; ++k)
        C[(size_t)(row0 + m * 16 + k) * Ndim + c] = sv * acc[m][n][k] + bv[n];
    }
}

extern "C" void kernel_launch(void* const* d_in, const int* in_sizes, int n_in,
                              void* d_out, int out_size, void* d_ws, size_t ws_size,
                              hipStream_t stream) {
  const float* x = (const float*)d_in[0];
  const int* pos = (const int*)d_in[1];
  const int* neg = (const int*)d_in[2];
  const float* scale = (const float*)d_in[3];
  const float* bias = (const float*)d_in[4];
  float* out = (float*)d_out;

  ushort_t* xb = (ushort_t*)d_ws;                        // 32 MB: x as bf16 [M][K]
  ushort_t* wb = xb + (size_t)Mdim * Kdim;               // 32 MB: W as bf16 [N][K]

  cvt_x_kernel<<<(Mdim * Kdim) / (256 * 8), 256, 0, stream>>>(x, xb);
  unpack_w_kernel<<<(Ndim * (Kdim / 8)) / (256 * 4), 256, 0, stream>>>(pos, neg, wb);
  gemm_kernel<<<dim3((Mdim / 256) * (Ndim / 256)), 512, 0, stream>>>(xb, wb, out, scale, bias);
}

// Round 4
// 236.073 us; speedup vs baseline: 1.3507x; 1.0163x over previous
//
#include <hip/hip_runtime.h>
#include <hip/hip_bf16.h>

typedef unsigned short ushort_t;
typedef unsigned int uint_t;

typedef __attribute__((ext_vector_type(8))) short bf16x8;
typedef __attribute__((ext_vector_type(4))) float f32x4;
typedef __attribute__((ext_vector_type(8))) unsigned short u16x8;

constexpr int Mdim = 4096;  // tokens
constexpr int Ndim = 4096;  // out features
constexpr int Kdim = 4096;  // in features
constexpr int K2 = Kdim * 2;          // global row stride in bytes
constexpr int NIT = Kdim / 128;       // 32 iterations, 2 K-tiles (BK=64) each

__device__ __forceinline__ ushort_t f2bf(float f) {
  uint_t u = __float_as_uint(f);
  u += 0x7fffu + ((u >> 16) & 1u);   // round-to-nearest-even
  return (ushort_t)(u >> 16);
}

// ---------------- fused pre-pass: x f32 -> bf16  |  bitmasks -> bf16 W ----------------
constexpr int CVT_BLOCKS = (Mdim * Kdim) / (256 * 8);          // 8192
constexpr int UNPACK_BLOCKS = (Ndim * (Kdim / 8)) / (256 * 4); // 2048

__global__ void __launch_bounds__(256) prep_kernel(const float* __restrict__ x,
                                                   ushort_t* __restrict__ xb,
                                                   const int* __restrict__ pos,
                                                   const int* __restrict__ neg,
                                                   ushort_t* __restrict__ wb) {
  const int b = blockIdx.x;
  if (b < CVT_BLOCKS) {
    const size_t t = (size_t)b * 256 + threadIdx.x;
    const float4* p = reinterpret_cast<const float4*>(x) + t * 2;
    float4 a = p[0], c = p[1];
    u16x8 o;
    o[0] = f2bf(a.x); o[1] = f2bf(a.y); o[2] = f2bf(a.z); o[3] = f2bf(a.w);
    o[4] = f2bf(c.x); o[5] = f2bf(c.y); o[6] = f2bf(c.z); o[7] = f2bf(c.w);
    *reinterpret_cast<u16x8*>(xb + t * 8) = o;
  } else {
    const size_t t = (size_t)(b - CVT_BLOCKS) * 256 + threadIdx.x;
    const int4 p = reinterpret_cast<const int4*>(pos)[t];
    const int4 q = reinterpret_cast<const int4*>(neg)[t];
    const int pv[4] = {p.x, p.y, p.z, p.w};
    const int nv[4] = {q.x, q.y, q.z, q.w};
    ushort_t* dst = wb + t * 32;
#pragma unroll
    for (int e = 0; e < 4; ++e) {
      u16x8 v;
#pragma unroll
      for (int j = 0; j < 8; ++j) {
        const int pb = (pv[e] >> (7 - j)) & 1;
        const int nb = (nv[e] >> (7 - j)) & 1;
        const int d = pb - nb;                     // {-1,0,+1}
        v[j] = (d == 1) ? (ushort_t)0x3F80 : ((d == -1) ? (ushort_t)0xBF80 : (ushort_t)0);
      }
      *reinterpret_cast<u16x8*>(dst + e * 8) = v;
    }
  }
}

// ---------------- 256x256 pipelined 8-window GEMM ----------------
#define GLD16(gp, lp)                                                     \
  __builtin_amdgcn_global_load_lds(                                       \
      (const __attribute__((address_space(1))) void*)(gp),                \
      (__attribute__((address_space(3))) void*)(lp), 16, 0, 0)

#define VMCNT(N) asm volatile("s_waitcnt vmcnt(" #N ")" ::: "memory")

#define BARRIER() do {                          \
  __builtin_amdgcn_sched_barrier(0);            \
  __builtin_amdgcn_s_barrier();                 \
  __builtin_amdgcn_sched_barrier(0);            \
} while (0)

// LDS map (131072 B total):
//   A: buf*32768 + half*16384 + row*128 + swizzled_col   (bufs at 0, 32768)
//   B: 65536 + buf*32768 + half*16384 + row*128 + swizzled_col
// Swizzle (T2, involution): phys_col = logical_col ^ ((row&7)<<4)

#define STAGE_A(BUF, HALF, KT) do {                                                    \
  const char* g_ = Ab + gAoff + (size_t)(HALF) * (128 * (size_t)K2) + (size_t)(KT) * 128; \
  char* l_ = ldsw + (BUF) * 32768 + (HALF) * 16384;                                    \
  GLD16(g_, l_);                                                                       \
  GLD16(g_ + (size_t)64 * K2, l_ + 8192);                                              \
} while (0)

#define STAGE_B(BUF, HALF, KT) do {                                                    \
  const char* g_ = Bb + gBoff + (size_t)(HALF) * (128 * (size_t)K2) + (size_t)(KT) * 128; \
  char* l_ = ldsw + 65536 + (BUF) * 32768 + (HALF) * 16384;                            \
  GLD16(g_, l_);                                                                       \
  GLD16(g_ + (size_t)64 * K2, l_ + 8192);                                              \
} while (0)

#define LDA(BUF, M, KK) (*(const bf16x8*)(lds + (BUF) * 32768 + aRowBase + (M) * 2048 + acol[KK]))
#define LDB(BUF, N, KK) (*(const bf16x8*)(lds + 65536 + (BUF) * 32768 + bRowBase + (N) * 2048 + acol[KK]))

// Prefetch A fragments for quadrant RQ of buffer RB into register bank BANK
// af[0]=k0 even-M, af[1]=k1 even-M, af[2]=k0 odd-M, af[3]=k1 odd-M
#define READS_A(BANK, RB, RQ) do {                                                     \
  af##BANK[0] = LDA(RB, 2*(RQ),   0); af##BANK[1] = LDA(RB, 2*(RQ),   1);              \
  af##BANK[2] = LDA(RB, 2*(RQ)+1, 0); af##BANK[3] = LDA(RB, 2*(RQ)+1, 1);              \
} while (0)

// Load one k-half of B fragments of buffer CB (4 x ds_read_b128), reusing vb[.][KK]
#define READS_B_HALF(CB, KK) do {                                                      \
  vb[0][KK] = LDB(CB, 0, KK); vb[1][KK] = LDB(CB, 1, KK);                              \
  vb[2][KK] = LDB(CB, 2, KK); vb[3][KK] = LDB(CB, 3, KK);                              \
} while (0)

// 8 MFMAs: k-half KK of quadrant Q on register bank BANK
#define MFMA8(BANK, Q, KK) do {                                                        \
  __builtin_amdgcn_s_setprio(1);                                                       \
  _Pragma("unroll")                                                                    \
  for (int n_ = 0; n_ < 4; ++n_) {                                                     \
    acc[2*(Q)][n_]   = __builtin_amdgcn_mfma_f32_16x16x32_bf16(af##BANK[0+(KK)], vb[n_][KK], acc[2*(Q)][n_],   0, 0, 0); \
    acc[2*(Q)+1][n_] = __builtin_amdgcn_mfma_f32_16x16x32_bf16(af##BANK[2+(KK)], vb[n_][KK], acc[2*(Q)+1][n_], 0, 0, 0); \
  }                                                                                    \
  __builtin_amdgcn_s_setprio(0);                                                       \
} while (0)

__global__ void __launch_bounds__(512, 2) gemm_kernel(const ushort_t* __restrict__ A,
                                                      const ushort_t* __restrict__ B,
                                                      float* __restrict__ C,
                                                      const float* __restrict__ scale_p,
                                                      const float* __restrict__ bias) {
  __shared__ char lds[131072];

  // T1: XCD-aware block swizzle (256 wgs, 8 XCDs, bijective)
  const int bid = blockIdx.x;
  const int swz = (bid & 7) * 32 + (bid >> 3);
  const int m0 = (swz >> 4) * 256;
  const int n0 = (swz & 15) * 256;

  const int tid = threadIdx.x;
  const int wid = tid >> 6;
  const int lane = tid & 63;
  const int wr = wid >> 2;   // 0..1 -> M half
  const int wc = wid & 3;    // 0..3 -> N quarter

  // Pin scale/bias loads before the counted-vmcnt region
  float sv = *scale_p;
  float bv[4];
#pragma unroll
  for (int n = 0; n < 4; ++n) bv[n] = bias[n0 + wc * 64 + n * 16 + (lane & 15)];
  asm volatile("" : "+v"(sv), "+v"(bv[0]), "+v"(bv[1]), "+v"(bv[2]), "+v"(bv[3]));

  // Staging addressing: thread covers segment s = tid of each 8KB region.
  // LDS dest linear; global source col pre-swizzled (involution) so swizzled ds_read sees logical data.
  const int srow = tid >> 3;                                  // 0..63
  const int scol = 16 * ((tid & 7) ^ (srow & 7));             // pre-swizzled source col-byte
  const char* Ab = (const char*)A;
  const char* Bb = (const char*)B;
  const size_t gAoff = (size_t)(m0 + srow) * K2 + scol;
  const size_t gBoff = (size_t)(n0 + srow) * K2 + scol;
  char* ldsw = lds + wid * 1024;   // wave-uniform LDS base component

  // Fragment read addressing (swizzled col)
  const int acol[2] = { (0  + ((lane >> 4) << 4)) ^ ((lane & 7) << 4),
                        (64 + ((lane >> 4) << 4)) ^ ((lane & 7) << 4) };
  const int aRowBase = wr * 16384 + (lane & 15) * 128;
  const int bRowBase = (wc >> 1) * 16384 + ((wc & 1) * 64 + (lane & 15)) * 128;

  f32x4 acc[8][4] = {};
  bf16x8 af0[4], af1[4];    // double-banked A fragments (pipelined one window ahead)
  bf16x8 vb[4][2];          // B fragments, k-halves pipelined in-place (WAR by program order)

  // Prologue: stage tile0 (buf0: B then A) + tile1's B (buf1); drain tile0; prefetch W0 operands.
  STAGE_B(0, 0, 0); STAGE_B(0, 1, 0);
  STAGE_A(0, 0, 0); STAGE_A(0, 1, 0);
  STAGE_B(1, 0, 1); STAGE_B(1, 1, 1);
  VMCNT(4);
  BARRIER();
  READS_A(0, 0, 0);
  READS_B_HALF(0, 0);

#pragma unroll 1
  for (int i = 0; i < NIT - 1; ++i) {
    const int t1 = 2 * i + 1, tn = 2 * i + 2;
    // ---- tile t0 (buf0) ----
    BARRIER(); STAGE_A(1, 0, t1); STAGE_A(1, 1, t1);               // W0
               READS_B_HALF(0, 1); READS_A(1, 0, 1);
               MFMA8(0, 0, 0); MFMA8(0, 0, 1);
    BARRIER(); STAGE_B(0, 0, tn);                                  // W1
               READS_A(0, 0, 2); MFMA8(1, 1, 0); MFMA8(1, 1, 1);
    BARRIER(); STAGE_B(0, 1, tn);                                  // W2
               READS_A(1, 0, 3); MFMA8(0, 2, 0); MFMA8(0, 2, 1);
    VMCNT(4);
    BARRIER(); READS_A(0, 1, 0);                                   // W3 (buf1 published)
               MFMA8(1, 3, 0); READS_B_HALF(1, 0); MFMA8(1, 3, 1);
    // ---- tile t1 (buf1) ----
    BARRIER(); STAGE_A(0, 0, tn);                                  // W4
               READS_B_HALF(1, 1); READS_A(1, 1, 1);
               MFMA8(0, 0, 0); MFMA8(0, 0, 1);
    BARRIER(); STAGE_A(0, 1, tn);                                  // W5
               READS_A(0, 1, 2); MFMA8(1, 1, 0); MFMA8(1, 1, 1);
    BARRIER(); STAGE_B(1, 0, t1 + 2);                              // W6
               READS_A(1, 1, 3); MFMA8(0, 2, 0); MFMA8(0, 2, 1);
    VMCNT(2);
    BARRIER(); STAGE_B(1, 1, t1 + 2);                              // W7 (buf0(tn) published)
               READS_A(0, 0, 0);
               MFMA8(1, 3, 0); READS_B_HALF(0, 0); MFMA8(1, 3, 1);
  }
  {
    // Final iteration: tiles 2*NIT-2 (buf0), 2*NIT-1 (buf1); only A(last) still to stage.
    BARRIER(); STAGE_A(1, 0, 2 * NIT - 1); STAGE_A(1, 1, 2 * NIT - 1);
               READS_B_HALF(0, 1); READS_A(1, 0, 1);
               MFMA8(0, 0, 0); MFMA8(0, 0, 1);
    BARRIER(); READS_A(0, 0, 2); MFMA8(1, 1, 0); MFMA8(1, 1, 1);
    BARRIER(); READS_A(1, 0, 3); MFMA8(0, 2, 0); MFMA8(0, 2, 1);
    VMCNT(0);
    BARRIER(); READS_A(0, 1, 0);
               MFMA8(1, 3, 0); READS_B_HALF(1, 0); MFMA8(1, 3, 1);
    BARRIER(); READS_B_HALF(1, 1); READS_A(1, 1, 1);
               MFMA8(0, 0, 0); MFMA8(0, 0, 1);
    BARRIER(); READS_A(0, 1, 2); MFMA8(1, 1, 0); MFMA8(1, 1, 1);
    BARRIER(); READS_A(1, 1, 3); MFMA8(0, 2, 0); MFMA8(0, 2, 1);
    BARRIER(); MFMA8(1, 3, 0); MFMA8(1, 3, 1);
  }

  // Epilogue: C/D layout col = lane&15, row = (lane>>4)*4 + reg
  const int row0 = m0 + wr * 128 + ((lane >> 4) << 2);
  const int col0 = n0 + wc * 64 + (lane & 15);
#pragma unroll
  for (int m = 0; m < 8; ++m)
#pragma unroll
    for (int n = 0; n < 4; ++n) {
      const int c = col0 + n * 16;
#pragma unroll
      for (int k = 0; k < 4; ++k)
        C[(size_t)(row0 + m * 16 + k) * Ndim + c] = sv * acc[m][n][k] + bv[n];
    }
}

extern "C" void kernel_launch(void* const* d_in, const int* in_sizes, int n_in,
                              void* d_out, int out_size, void* d_ws, size_t ws_size,
                              hipStream_t stream) {
  const float* x = (const float*)d_in[0];
  const int* pos = (const int*)d_in[1];
  const int* neg = (const int*)d_in[2];
  const float* scale = (const float*)d_in[3];
  const float* bias = (const float*)d_in[4];
  float* out = (float*)d_out;

  ushort_t* xb = (ushort_t*)d_ws;                        // 32 MB: x as bf16 [M][K]
  ushort_t* wb = xb + (size_t)Mdim * Kdim;               // 32 MB: W as bf16 [N][K]

  prep_kernel<<<CVT_BLOCKS + UNPACK_BLOCKS, 256, 0, stream>>>(x, xb, pos, neg, wb);
  gemm_kernel<<<dim3((Mdim / 256) * (Ndim / 256)), 512, 0, stream>>>(xb, wb, out, scale, bias);
}